// Round 4
// baseline (164.799 us; speedup 1.0000x reference)
//
#include <hip/hip_runtime.h>
#include <math.h>

constexpr int NH     = 7;
constexpr int NDIST  = 4;
constexpr int NTHETA = 8;
constexpr int EDIM   = 16;
constexpr int NPB    = 8;    // points per group
constexpr int BLOCK  = 256;
constexpr int MAXGRID = 2048;   // 8 blocks/CU; persistent, ~4 groups/block

typedef float f32x4 __attribute__((ext_vector_type(4)));

__global__ __launch_bounds__(BLOCK) void grid_layer_kernel(
    const float* __restrict__ x,        // (N, 16)
    const float* __restrict__ coords,   // (2, N): [0]=lon, [1]=lat
    const float* __restrict__ sigma_p,  // (1)
    const float* __restrict__ kappa_p,  // (1)
    const int*   __restrict__ lidx,     // (N)
    const int*   __restrict__ adjc,     // (N, 7)
    float*       __restrict__ out,      // (N, 4, 8, 16)
    int N)
{
    // Double-buffered LDS: one barrier per group (see proof in session log).
    __shared__ float4 xs [2][NPB][NH][EDIM / 4];
    __shared__ float4 vm4[2][NPB][NH][2];
    __shared__ float4 nd4[2][NPB][NH];

    const int tid = threadIdx.x;
    const bool stg = (tid < NPB * NH * 4);      // 224 staging threads
    const int p   = tid >> 2, q = tid & 3;
    const int snl = p / NH, sk = p - snl * NH;  // staging (point, neighbor)
    const bool geo = stg && (q == 0);           // 56 geometry threads

    const float inv_s = 1.0f / sigma_p[0];
    const float kappa = kappa_p[0];

    const int S  = (int)gridDim.x;              // group stride
    const int nG = (N + NPB - 1) / NPB;
    const int g0 = blockIdx.x;

    // ---- pipeline registers ----
    int    idxNxt = 0, idx0Nxt = 0;             // adjc idx for group g+S
    float4 xR = make_float4(0.f, 0.f, 0.f, 0.f);
    float  lon1R = 0.f, lat1R = 0.f, lon2R = 0.f, lat2R = 0.f;

    // ---- prologue: idx chain + gathers for g0; idx chain for g0+S ----
    if (stg) {
        const int n  = g0 * NPB + snl;
        const int nn = (n < N) ? n : (N - 1);   // clamp; phase-2 guard skips
        const int li = lidx[nn];
        const int idx  = adjc[(size_t)li * NH + sk];
        const int idx0 = adjc[(size_t)li * NH];
        xR = ((const float4*)(x + (size_t)idx * EDIM))[q];
        if (geo) {
            lon1R = coords[idx0]; lat1R = coords[N + idx0];
            lon2R = coords[idx];  lat2R = coords[N + idx];
        }
        const int g1 = g0 + S;
        if (g1 < nG) {
            const int n1  = g1 * NPB + snl;
            const int nn1 = (n1 < N) ? n1 : (N - 1);
            const int li1 = lidx[nn1];
            idxNxt = adjc[(size_t)li1 * NH + sk];
            if (geo) idx0Nxt = adjc[(size_t)li1 * NH];
        }
    }

    int buf = 0;
    for (int g = g0; g < nG; g += S, buf ^= 1) {
        // ---- A: staged regs -> LDS[buf]; weights from coord regs ----
        if (stg) {
            xs[buf][snl][sk][q] = xR;
            if (geo) {
                float s1, c1, s2, c2, sd, cd;
                __sincosf(lat1R, &s1, &c1);
                __sincosf(lat2R, &s2, &c2);
                __sincosf(lon2R - lon1R, &sd, &cd);
                const float tcc = c2 * cd;
                float cosd = fmaf(s1, s2, c1 * tcc);
                cosd = fminf(fmaxf(cosd, -1.0f + 1e-7f), 1.0f - 1e-7f);
                const float dist = acosf(cosd);
                // bearing; separate products so k=0 / duplicate neighbors
                // cancel exactly (fl(c*s) - fl(s*c) == 0) like the reference.
                const float p1 = c1 * s2;
                const float p2 = s1 * tcc;
                const float xb = p1 - p2;
                const float yb = sd * c2;
                const float r2 = xb * xb + yb * yb;
                float cphi = 1.0f, sphi = 0.0f;    // atan2(0,0) = 0
                if (r2 > 1e-12f) {                  // residue r2<=4e-17 vs
                    const float ri = __builtin_amdgcn_rsqf(r2);  // genuine ~3e-8
                    cphi = xb * ri; sphi = yb * ri;
                }
                const float A = kappa * cphi;
                const float B = kappa * sphi;
                const float U = 0.70710678118f * (A + B);
                const float V = 0.70710678118f * (A - B);
                float4 va, vb;
                va.x = __expf(-A); va.y = __expf(-U); va.z = __expf(-B); va.w = __expf(V);
                vb.x = __expf(A);  vb.y = __expf(U);  vb.z = __expf(B);  vb.w = __expf(-V);
                vm4[buf][snl][sk][0] = va;
                vm4[buf][snl][sk][1] = vb;
                const float di = dist * inv_s;
                const float z1 = fmaf(0.066666667f, inv_s, -di);
                const float z2 = fmaf(0.133333333f, inv_s, -di);
                const float z3 = fmaf(0.2f,         inv_s, -di);
                float4 nd;
                nd.x = __expf(-0.5f * di * di);
                nd.y = __expf(-0.5f * z1 * z1);
                nd.z = __expf(-0.5f * z2 * z2);
                nd.w = __expf(-0.5f * z3 * z3);
                nd4[buf][snl][sk] = nd;
            }
        }
        __syncthreads();

        // ---- B: issue next group's gathers + idx chain for g+2S ----
        // Latency hides under phase-2 below; consumed at next iter's A.
        const int gN1 = g + S;
        if (stg && gN1 < nG) {
            xR = ((const float4*)(x + (size_t)idxNxt * EDIM))[q];
            if (geo) {
                lon1R = coords[idx0Nxt]; lat1R = coords[N + idx0Nxt];
                lon2R = coords[idxNxt];  lat2R = coords[N + idxNxt];
            }
            const int gN2 = g + 2 * S;
            if (gN2 < nG) {
                const int n2  = gN2 * NPB + snl;
                const int nn2 = (n2 < N) ? n2 : (N - 1);
                const int li2 = lidx[nn2];
                idxNxt = adjc[(size_t)li2 * NH + sk];
                if (geo) idx0Nxt = adjc[(size_t)li2 * NH];
            }
        }

        // ---- C: phase 2 for g from LDS[buf] ----
        const int nl = tid >> 5;     // 0..7
        const int j  = tid & 31;
        const int t  = j >> 2;       // 0..7
        const int e4 = j & 3;        // 0..3
        const int n  = g * NPB + nl;
        if (n < N) {
            float  sw[NDIST] = {0.f, 0.f, 0.f, 0.f};
            float4 acc[NDIST];
            #pragma unroll
            for (int d = 0; d < NDIST; ++d) acc[d] = make_float4(0.f, 0.f, 0.f, 0.f);

            #pragma unroll
            for (int k = 0; k < NH; ++k) {
                const float  vmk = ((const float*)&vm4[buf][nl][k][0])[t];
                const float4 nd  = nd4[buf][nl][k];
                const float4 xv  = xs[buf][nl][k][e4];
                const float w0 = vmk * nd.x;
                const float w1 = vmk * nd.y;
                const float w2 = vmk * nd.z;
                const float w3 = vmk * nd.w;
                sw[0] += w0; sw[1] += w1; sw[2] += w2; sw[3] += w3;
                acc[0].x = fmaf(w0, xv.x, acc[0].x);
                acc[0].y = fmaf(w0, xv.y, acc[0].y);
                acc[0].z = fmaf(w0, xv.z, acc[0].z);
                acc[0].w = fmaf(w0, xv.w, acc[0].w);
                acc[1].x = fmaf(w1, xv.x, acc[1].x);
                acc[1].y = fmaf(w1, xv.y, acc[1].y);
                acc[1].z = fmaf(w1, xv.z, acc[1].z);
                acc[1].w = fmaf(w1, xv.w, acc[1].w);
                acc[2].x = fmaf(w2, xv.x, acc[2].x);
                acc[2].y = fmaf(w2, xv.y, acc[2].y);
                acc[2].z = fmaf(w2, xv.z, acc[2].z);
                acc[2].w = fmaf(w2, xv.w, acc[2].w);
                acc[3].x = fmaf(w3, xv.x, acc[3].x);
                acc[3].y = fmaf(w3, xv.y, acc[3].y);
                acc[3].z = fmaf(w3, xv.z, acc[3].z);
                acc[3].w = fmaf(w3, xv.w, acc[3].w);
            }

            float* outp = out + (size_t)n * (NDIST * NTHETA * EDIM);
            #pragma unroll
            for (int d = 0; d < NDIST; ++d) {
                const float inv = __builtin_amdgcn_rcpf(sw[d] + 1e-10f);
                f32x4 o;
                o.x = acc[d].x * inv;
                o.y = acc[d].y * inv;
                o.z = acc[d].z * inv;
                o.w = acc[d].w * inv;
                __builtin_nontemporal_store(
                    o, (f32x4*)(outp + (d * NTHETA * EDIM) + (t * EDIM) + e4 * 4));
            }
        }
        // no trailing barrier: double-buffered LDS; bar at A(i+1) orders
        // C(i) reads (buf) against A(i+2) writes (buf).
    }
}

extern "C" void kernel_launch(void* const* d_in, const int* in_sizes, int n_in,
                              void* d_out, int out_size, void* d_ws, size_t ws_size,
                              hipStream_t stream) {
    const float* x      = (const float*)d_in[0];
    const float* coords = (const float*)d_in[1];
    const float* sigma  = (const float*)d_in[2];
    const float* kappa  = (const float*)d_in[3];
    const int*   lidx   = (const int*)d_in[4];
    const int*   adjc   = (const int*)d_in[5];
    float*       out    = (float*)d_out;

    const int N  = in_sizes[4];  // local_indices has N elements (B=1)
    const int nG = (N + NPB - 1) / NPB;
    const int grid = (nG < MAXGRID) ? nG : MAXGRID;
    hipLaunchKernelGGL(grid_layer_kernel, dim3(grid), dim3(BLOCK), 0, stream,
                       x, coords, sigma, kappa, lidx, adjc, out, N);
}